// Round 2
// baseline (541.288 us; speedup 1.0000x reference)
//
#include <hip/hip_runtime.h>
#include <hip/hip_bf16.h>

#define NN 100000
#define ENUM 25000
#define NNZ_C 200000
// D = 128, H = 4, F = 128, Wlin: [128,512]

__device__ __forceinline__ float bf2f(unsigned short v) {
    return __uint_as_float(((unsigned)v) << 16);
}
__device__ __forceinline__ unsigned short f2bf(float x) {
    unsigned u = __float_as_uint(x);
    unsigned r = (u + 0x7fff + ((u >> 16) & 1)) >> 16;   // round-to-nearest-even
    return (unsigned short)r;
}

// ---------------- GEMM: C[M,NC] = A[M,128] @ W[128,NC] (+bias) (+resid) ----
template <bool BF16OUT>
__global__ __launch_bounds__(256) void gemm_k(
    const float* __restrict__ A, const float* __restrict__ W,
    const float* __restrict__ bias, const float* __restrict__ resid,
    void* __restrict__ Cv, int M, int NC)
{
    __shared__ float As[64][68];
    __shared__ float Ws[64][68];
    const int tid = threadIdx.x;
    const int r0 = blockIdx.x * 64;
    const int c0 = blockIdx.y * 64;
    const int rg = tid >> 4, cg = tid & 15;

    float acc[4][4] = {};

    for (int kc = 0; kc < 128; kc += 64) {
        __syncthreads();
        {
            int kq = tid & 15;
            int rr = tid >> 4;
            #pragma unroll
            for (int it = 0; it < 4; it++) {
                int r = r0 + rr; if (r > M - 1) r = M - 1;
                const float4 a = *(const float4*)(A + (size_t)r * 128 + kc + kq * 4);
                *(float4*)&As[rr][kq * 4] = a;
                rr += 16;
            }
            int c4 = tid & 15;
            int kk = tid >> 4;
            #pragma unroll
            for (int it = 0; it < 4; it++) {
                const float4 w = *(const float4*)(W + (size_t)(kc + kk) * NC + c0 + c4 * 4);
                *(float4*)&Ws[kk][c4 * 4] = w;
                kk += 16;
            }
        }
        __syncthreads();
        #pragma unroll
        for (int k4 = 0; k4 < 16; k4++) {
            float4 a4[4], b4[4];
            #pragma unroll
            for (int i = 0; i < 4; i++) a4[i] = *(const float4*)&As[rg * 4 + i][k4 * 4];
            #pragma unroll
            for (int j = 0; j < 4; j++) b4[j] = *(const float4*)&Ws[k4 * 4 + j][cg * 4];
            #pragma unroll
            for (int i = 0; i < 4; i++) {
                const float* av = (const float*)&a4[i];
                #pragma unroll
                for (int kk = 0; kk < 4; kk++) {
                    const float* bv = (const float*)&b4[kk];
                    acc[i][0] += av[kk] * bv[0];
                    acc[i][1] += av[kk] * bv[1];
                    acc[i][2] += av[kk] * bv[2];
                    acc[i][3] += av[kk] * bv[3];
                }
            }
        }
    }

    #pragma unroll
    for (int i = 0; i < 4; i++) {
        const int r = r0 + rg * 4 + i;
        if (r < M) {
            const int c = c0 + cg * 4;
            float4 v = make_float4(acc[i][0], acc[i][1], acc[i][2], acc[i][3]);
            if (bias) { v.x += bias[c]; v.y += bias[c + 1]; v.z += bias[c + 2]; v.w += bias[c + 3]; }
            if (resid) {
                const float4 rv = *(const float4*)(resid + (size_t)r * NC + c);
                v.x += rv.x; v.y += rv.y; v.z += rv.z; v.w += rv.w;
            }
            if (BF16OUT) {
                ushort4 u;
                u.x = f2bf(v.x); u.y = f2bf(v.y); u.z = f2bf(v.z); u.w = f2bf(v.w);
                *(ushort4*)((unsigned short*)Cv + (size_t)r * NC + c) = u;
            } else {
                *(float4*)((float*)Cv + (size_t)r * NC + c) = v;
            }
        }
    }
}

// -------- edge aggregation: Eres[e,:] += (1/deg_e) * sum_j adj[k] * Xt[row[k],:] ----
__global__ __launch_bounds__(256) void edge_agg_k(
    const int* __restrict__ row, const float* __restrict__ adjv,
    const float* __restrict__ Xt, float* __restrict__ Eres)
{
    const int e = blockIdx.x * 2 + (threadIdx.x >> 7);
    const int f = threadIdx.x & 127;
    if (e >= ENUM) return;
    float acc = 0.f, deg = 0.f;
    #pragma unroll
    for (int j = 0; j < 8; j++) {
        const int k = e + j * ENUM;
        const float v = adjv[k];
        deg += v;
        acc += v * Xt[(size_t)row[k] * 128 + f];
    }
    Eres[(size_t)e * 128 + f] += acc / deg;
}

// -------- per-row attention dot (bf16 feat): out[m,h] = sum_f feat[m,h*128+f]*att[h*256+f] ----
__global__ __launch_bounds__(256) void att_dot_k(
    const unsigned short* __restrict__ feat, const float* __restrict__ att,
    float* __restrict__ out, int M)
{
    const int wid = (blockIdx.x * 256 + threadIdx.x) >> 6;
    const int lane = threadIdx.x & 63;
    if (wid >= M) return;
    const int h = lane >> 4;
    const int f0 = (lane & 15) * 8;
    const unsigned short* fp = feat + (size_t)wid * 512 + h * 128 + f0;
    const float* ap = att + h * 256 + f0;
    const uint4 u = *(const uint4*)fp;   // 8 bf16
    float s = 0.f;
    s += __uint_as_float(u.x << 16)        * ap[0];
    s += __uint_as_float(u.x & 0xFFFF0000u)* ap[1];
    s += __uint_as_float(u.y << 16)        * ap[2];
    s += __uint_as_float(u.y & 0xFFFF0000u)* ap[3];
    s += __uint_as_float(u.z << 16)        * ap[4];
    s += __uint_as_float(u.z & 0xFFFF0000u)* ap[5];
    s += __uint_as_float(u.w << 16)        * ap[6];
    s += __uint_as_float(u.w & 0xFFFF0000u)* ap[7];
    s += __shfl_xor(s, 1); s += __shfl_xor(s, 2);
    s += __shfl_xor(s, 4); s += __shfl_xor(s, 8);
    if ((lane & 15) == 0) out[(size_t)wid * 4 + h] = s;
}

__device__ __forceinline__ unsigned fkey_enc(float x) {
    unsigned u = __float_as_uint(x);
    return (u & 0x80000000u) ? ~u : (u | 0x80000000u);
}
__device__ __forceinline__ float fkey_dec(unsigned k) {
    unsigned u = (k & 0x80000000u) ? (k & 0x7fffffffu) : ~k;
    return __uint_as_float(u);
}

// -------- zero fill ----
__global__ __launch_bounds__(256) void zero_k(unsigned* __restrict__ p, int n)
{
    const int t = blockIdx.x * 256 + threadIdx.x;
    if (t < n) p[t] = 0u;
}

// -------- alpha = lrelu(ax[row]+ae[col]); atomic max per (row,h) ----
__global__ __launch_bounds__(256) void alpha_max_k(
    const int* __restrict__ row, const int* __restrict__ col,
    const float* __restrict__ ax, const float* __restrict__ ae,
    float* __restrict__ alpha, unsigned* __restrict__ nmax)
{
    const int t = blockIdx.x * 256 + threadIdx.x;
    if (t >= NNZ_C * 4) return;
    const int k = t >> 2, h = t & 3;
    const int r = row[k], c = col[k];
    float a = ax[(size_t)r * 4 + h] + ae[(size_t)c * 4 + h];
    a = (a >= 0.f) ? a : 0.2f * a;
    alpha[t] = a;
    atomicMax(nmax + (size_t)r * 4 + h, fkey_enc(a));
}

// -------- exp(alpha - max); atomic sum per (row,h); Dn accumulation ----
__global__ __launch_bounds__(256) void alpha_exp_k(
    const int* __restrict__ row, const int* __restrict__ col,
    const float* __restrict__ adjv, float* __restrict__ alpha,
    const unsigned* __restrict__ nmax, float* __restrict__ nsum,
    float* __restrict__ Dn)
{
    const int t = blockIdx.x * 256 + threadIdx.x;
    if (t >= NNZ_C * 4) return;
    const int k = t >> 2, h = t & 3;
    const int r = row[k];
    const float m = fkey_dec(nmax[(size_t)r * 4 + h]);
    const float ex = __expf(alpha[t] - m);
    alpha[t] = ex;
    atomicAdd(nsum + (size_t)r * 4 + h, ex);
    if (h == 0) atomicAdd(Dn + r, adjv[col[k]]);
}

// -------- alpha /= nsum[row] ----
__global__ __launch_bounds__(256) void alpha_norm_k(
    const int* __restrict__ row, float* __restrict__ alpha,
    const float* __restrict__ nsum)
{
    const int t = blockIdx.x * 256 + threadIdx.x;
    if (t >= NNZ_C * 4) return;
    const int k = t >> 2, h = t & 3;
    alpha[t] /= nsum[(size_t)row[k] * 4 + h];
}

// -------- out_e[e,h,f] = (1/8) sum_j alpha[k,h] * Xlin[row[k], h*128+f] ----
__global__ __launch_bounds__(256) void out_e_k(
    const int* __restrict__ row, const float* __restrict__ alpha,
    const unsigned short* __restrict__ Xlin, float* __restrict__ out_e)
{
    const int e = blockIdx.x * 2 + (threadIdx.x >> 7);
    const int f = threadIdx.x & 127;
    if (e >= ENUM) return;
    float a0 = 0.f, a1 = 0.f, a2 = 0.f, a3 = 0.f;
    #pragma unroll
    for (int j = 0; j < 8; j++) {
        const int k = e + j * ENUM;
        const int r = row[k];
        const unsigned short* xp = Xlin + (size_t)r * 512 + f;
        const float4 al = *(const float4*)(alpha + (size_t)k * 4);
        a0 += al.x * bf2f(xp[0]);
        a1 += al.y * bf2f(xp[128]);
        a2 += al.z * bf2f(xp[256]);
        a3 += al.w * bf2f(xp[384]);
    }
    float* op = out_e + (size_t)e * 512 + f;
    op[0]   = 0.125f * a0;
    op[128] = 0.125f * a1;
    op[256] = 0.125f * a2;
    op[384] = 0.125f * a3;
}

// -------- Xres init with bias_conv ----
__global__ __launch_bounds__(256) void xres_init_k(
    float* __restrict__ Xres, const float* __restrict__ bias)
{
    const int t = blockIdx.x * 256 + threadIdx.x;
    if (t < NN * 128) Xres[t] = bias[t & 127];
}

// -------- final scatter: Xres[row[k],f] += (1/(4*Dn)) sum_h alpha[k,h]*out_e[col[k],h,f] ----
__global__ __launch_bounds__(256) void scatter_k(
    const int* __restrict__ row, const int* __restrict__ col,
    const float* __restrict__ alpha, const float* __restrict__ Dn,
    const float* __restrict__ out_e, float* __restrict__ Xres)
{
    const int k = blockIdx.x * 2 + (threadIdx.x >> 7);
    const int f = threadIdx.x & 127;
    if (k >= NNZ_C) return;
    const int r = row[k], c = col[k];
    const float w = 0.25f / Dn[r];
    const float4 al = *(const float4*)(alpha + (size_t)k * 4);
    const float* ep = out_e + (size_t)c * 512 + f;
    const float v = w * (al.x * ep[0] + al.y * ep[128] +
                         al.z * ep[256] + al.w * ep[384]);
    atomicAdd(Xres + (size_t)r * 128 + f, v);
}

extern "C" void kernel_launch(void* const* d_in, const int* in_sizes, int n_in,
                              void* d_out, int out_size, void* d_ws, size_t ws_size,
                              hipStream_t stream)
{
    const float* X         = (const float*)d_in[0];
    const float* E         = (const float*)d_in[1];
    const int*   adj       = (const int*)d_in[2];
    const float* adjv      = (const float*)d_in[3];
    const float* Wn        = (const float*)d_in[4];
    const float* bn        = (const float*)d_in[5];
    const float* We        = (const float*)d_in[6];
    const float* be        = (const float*)d_in[7];
    const float* Wlin      = (const float*)d_in[8];
    const float* att       = (const float*)d_in[9];
    const float* bias_conv = (const float*)d_in[10];
    const int* row = adj;
    const int* col = adj + NNZ_C;

    float* Xres = (float*)d_out;
    float* Eres = Xres + (size_t)NN * 128;

    // workspace layout, ~162 MB total
    char* ws = (char*)d_ws;
    float* buf0 = (float*)ws;                               // 12.8M floats: Xt -> elin(bf16) -> out_e
    ws += (size_t)NN * 128 * 4;                             // 51.2 MB
    unsigned short* Xlin = (unsigned short*)ws;             // N*512 bf16
    ws += (size_t)NN * 512 * 2;                             // 102.4 MB
    float* ax = (float*)ws;    ws += (size_t)NN * 4 * 4;    // 1.6 MB
    float* ae = (float*)ws;    ws += (size_t)ENUM * 4 * 4;  // 0.4 MB
    float* alpha = (float*)ws; ws += (size_t)NNZ_C * 4 * 4; // 3.2 MB
    unsigned* nmax = (unsigned*)ws;                         // N*4 (nmax,nsum,Dn contiguous)
    ws += (size_t)NN * 4 * 4;
    float* nsum = (float*)ws;  ws += (size_t)NN * 4 * 4;
    float* Dn = (float*)ws;    ws += (size_t)NN * 4;
    float* Xt = buf0;
    unsigned short* elin = (unsigned short*)buf0;
    float* out_e = buf0;

    // zero nmax + nsum + Dn (contiguous: N*4 + N*4 + N words)
    zero_k<<<(NN * 9 + 255) / 256, 256, 0, stream>>>(nmax, NN * 9);

    // 1. Xt = X @ Wn + bn
    gemm_k<false><<<dim3(1563, 2), 256, 0, stream>>>(X, Wn, bn, nullptr, Xt, NN, 128);
    // 2. Eres = E @ We + be + E
    gemm_k<false><<<dim3(391, 2), 256, 0, stream>>>(E, We, be, E, Eres, ENUM, 128);
    // 3. Eres += norm * agg
    edge_agg_k<<<ENUM / 2, 256, 0, stream>>>(row, adjv, Xt, Eres);
    // 4. Xlin = bf16(X @ Wlin)
    gemm_k<true><<<dim3(1563, 8), 256, 0, stream>>>(X, Wlin, nullptr, nullptr, Xlin, NN, 512);
    // 5. elin = bf16(Eres @ Wlin)  (Xt dead now)
    gemm_k<true><<<dim3(391, 8), 256, 0, stream>>>(Eres, Wlin, nullptr, nullptr, elin, ENUM, 512);
    // 6. attention dots
    att_dot_k<<<NN / 4, 256, 0, stream>>>(Xlin, att, ax, NN);
    att_dot_k<<<ENUM / 4, 256, 0, stream>>>(elin, att + 128, ae, ENUM);
    // 7-9. segment softmax over rows + Dn
    alpha_max_k<<<(NNZ_C * 4) / 256, 256, 0, stream>>>(row, col, ax, ae, alpha, nmax);
    alpha_exp_k<<<(NNZ_C * 4) / 256, 256, 0, stream>>>(row, col, adjv, alpha, nmax, nsum, Dn);
    alpha_norm_k<<<(NNZ_C * 4) / 256, 256, 0, stream>>>(row, alpha, nsum);
    // 10. node -> hyperedge aggregation (out_e reuses buf0; elin dead)
    out_e_k<<<ENUM / 2, 256, 0, stream>>>(row, alpha, Xlin, out_e);
    // 11-12. hyperedge -> node aggregation (+ bias, mean over heads)
    xres_init_k<<<(NN * 128) / 256, 256, 0, stream>>>(Xres, bias_conv);
    scatter_k<<<NNZ_C / 2, 256, 0, stream>>>(row, col, alpha, Dn, out_e, Xres);
}

// Round 3
// 362.520 us; speedup vs baseline: 1.4931x; 1.4931x over previous
//
#include <hip/hip_runtime.h>

#define NN 100000
#define ENUM 25000
#define NNZ_C 200000
// D = 128, H = 4, F = 128, Wlin: [128,512]

typedef __attribute__((ext_vector_type(8))) short bf16x8;
typedef __attribute__((ext_vector_type(4))) float f32x4;

__device__ __forceinline__ float bf2f(unsigned short v) {
    return __uint_as_float(((unsigned)v) << 16);
}
__device__ __forceinline__ unsigned short f2bf(float x) {
    unsigned u = __float_as_uint(x);
    unsigned r = (u + 0x7fff + ((u >> 16) & 1)) >> 16;   // round-to-nearest-even
    return (unsigned short)r;
}

// -------- f32 -> bf16 convert (4 elems/thread) --------
__global__ __launch_bounds__(256) void convbf_k(
    const float* __restrict__ in, unsigned short* __restrict__ out, int n4)
{
    const int t = blockIdx.x * 256 + threadIdx.x;
    if (t >= n4) return;
    const float4 a = ((const float4*)in)[t];
    ushort4 u;
    u.x = f2bf(a.x); u.y = f2bf(a.y); u.z = f2bf(a.z); u.w = f2bf(a.w);
    ((ushort4*)out)[t] = u;
}

// -------- W[128][NC] f32 -> Wt[NC][128] bf16 (transpose) --------
__global__ __launch_bounds__(256) void wtr_k(
    const float* __restrict__ W, unsigned short* __restrict__ Wt, int NC)
{
    const int t = blockIdx.x * 256 + threadIdx.x;
    if (t >= 128 * NC) return;
    const int c = t % NC, k = t / NC;
    Wt[c * 128 + k] = f2bf(W[t]);
}

// ---------------- MFMA GEMM: C[M,NC] = A[M,128] @ W[128,NC] (+bias)(+resid) ----
// A: bf16 row-major [M][128]; Wt: bf16 [NC][128] (pre-transposed)
template <bool BF16OUT>
__global__ __launch_bounds__(256) void gemm_mfma_k(
    const unsigned short* __restrict__ A, const unsigned short* __restrict__ Wt,
    const float* __restrict__ bias, const float* __restrict__ resid,
    void* __restrict__ Cv, int M, int NC)
{
    __shared__ unsigned short As[64 * 128];
    __shared__ unsigned short Bs[64 * 128];
    const int tid = threadIdx.x;
    const int r0 = blockIdx.x * 64;
    const int c0 = blockIdx.y * 64;

    // stage A-tile rows [r0,r0+64) and B-tile rows (=cols of C) [c0,c0+64), K=128
    {
        int rr = tid >> 4;
        const int kc = (tid & 15) * 8;
        #pragma unroll
        for (int it = 0; it < 4; it++) {
            int r = r0 + rr; if (r > M - 1) r = M - 1;
            const uint4 va = *(const uint4*)(A + (size_t)r * 128 + kc);
            const uint4 vb = *(const uint4*)(Wt + (size_t)(c0 + rr) * 128 + kc);
            const int idx = (rr * 128 + kc) ^ ((rr & 7) << 3);  // XOR swizzle (bytes<<4)
            *(uint4*)&As[idx] = va;
            *(uint4*)&Bs[idx] = vb;
            rr += 16;
        }
    }
    __syncthreads();

    const int lane = tid & 63;
    const int wid = tid >> 6;
    const int wr = wid >> 1, wc = wid & 1;     // wave -> 32x32 quadrant
    const int fr = lane & 15;
    const int kg = (lane >> 4) * 8;

    f32x4 acc[2][2] = {};

    #pragma unroll
    for (int ks = 0; ks < 4; ks++) {
        bf16x8 a[2], b[2];
        #pragma unroll
        for (int m = 0; m < 2; m++) {
            const int ar = wr * 32 + m * 16 + fr;
            const int idx = (ar * 128 + ks * 32 + kg) ^ ((ar & 7) << 3);
            a[m] = *(const bf16x8*)&As[idx];
        }
        #pragma unroll
        for (int n = 0; n < 2; n++) {
            const int br = wc * 32 + n * 16 + fr;
            const int idx = (br * 128 + ks * 32 + kg) ^ ((br & 7) << 3);
            b[n] = *(const bf16x8*)&Bs[idx];
        }
        #pragma unroll
        for (int m = 0; m < 2; m++)
            #pragma unroll
            for (int n = 0; n < 2; n++)
                acc[m][n] = __builtin_amdgcn_mfma_f32_16x16x32_bf16(a[m], b[n], acc[m][n], 0, 0, 0);
    }

    // epilogue: C row = (lane>>4)*4+j, col = lane&15 within each 16x16 frag
    #pragma unroll
    for (int m = 0; m < 2; m++) {
        #pragma unroll
        for (int n = 0; n < 2; n++) {
            const int c = c0 + wc * 32 + n * 16 + (lane & 15);
            #pragma unroll
            for (int j = 0; j < 4; j++) {
                const int r = r0 + wr * 32 + m * 16 + (lane >> 4) * 4 + j;
                if (r < M) {
                    float v = acc[m][n][j];
                    if (bias) v += bias[c];
                    if (resid) v += resid[(size_t)r * NC + c];
                    if (BF16OUT) ((unsigned short*)Cv)[(size_t)r * NC + c] = f2bf(v);
                    else         ((float*)Cv)[(size_t)r * NC + c] = v;
                }
            }
        }
    }
}

// -------- edge aggregation: Eres[e,:] += (1/deg_e) * sum_j adj[k] * Xt[row[k],:] ----
__global__ __launch_bounds__(256) void edge_agg_k(
    const int* __restrict__ row, const float* __restrict__ adjv,
    const unsigned short* __restrict__ Xt, float* __restrict__ Eres)
{
    const int e = blockIdx.x * 2 + (threadIdx.x >> 7);
    const int f = threadIdx.x & 127;
    if (e >= ENUM) return;
    float acc = 0.f, deg = 0.f;
    #pragma unroll
    for (int j = 0; j < 8; j++) {
        const int k = e + j * ENUM;
        const float v = adjv[k];
        deg += v;
        acc += v * bf2f(Xt[(size_t)row[k] * 128 + f]);
    }
    Eres[(size_t)e * 128 + f] += acc / deg;
}

// -------- per-row attention dot (bf16 feat) --------
__global__ __launch_bounds__(256) void att_dot_k(
    const unsigned short* __restrict__ feat, const float* __restrict__ att,
    float* __restrict__ out, int M)
{
    const int wid = (blockIdx.x * 256 + threadIdx.x) >> 6;
    const int lane = threadIdx.x & 63;
    if (wid >= M) return;
    const int h = lane >> 4;
    const int f0 = (lane & 15) * 8;
    const unsigned short* fp = feat + (size_t)wid * 512 + h * 128 + f0;
    const float* ap = att + h * 256 + f0;
    const uint4 u = *(const uint4*)fp;
    float s = 0.f;
    s += __uint_as_float(u.x << 16)         * ap[0];
    s += __uint_as_float(u.x & 0xFFFF0000u) * ap[1];
    s += __uint_as_float(u.y << 16)         * ap[2];
    s += __uint_as_float(u.y & 0xFFFF0000u) * ap[3];
    s += __uint_as_float(u.z << 16)         * ap[4];
    s += __uint_as_float(u.z & 0xFFFF0000u) * ap[5];
    s += __uint_as_float(u.w << 16)         * ap[6];
    s += __uint_as_float(u.w & 0xFFFF0000u) * ap[7];
    s += __shfl_xor(s, 1); s += __shfl_xor(s, 2);
    s += __shfl_xor(s, 4); s += __shfl_xor(s, 8);
    if ((lane & 15) == 0) out[(size_t)wid * 4 + h] = s;
}

__device__ __forceinline__ unsigned fkey_enc(float x) {
    unsigned u = __float_as_uint(x);
    return (u & 0x80000000u) ? ~u : (u | 0x80000000u);
}
__device__ __forceinline__ float fkey_dec(unsigned k) {
    unsigned u = (k & 0x80000000u) ? (k & 0x7fffffffu) : ~k;
    return __uint_as_float(u);
}

__global__ __launch_bounds__(256) void zero_k(unsigned* __restrict__ p, int n)
{
    const int t = blockIdx.x * 256 + threadIdx.x;
    if (t < n) p[t] = 0u;
}

__global__ __launch_bounds__(256) void alpha_max_k(
    const int* __restrict__ row, const int* __restrict__ col,
    const float* __restrict__ ax, const float* __restrict__ ae,
    float* __restrict__ alpha, unsigned* __restrict__ nmax)
{
    const int t = blockIdx.x * 256 + threadIdx.x;
    if (t >= NNZ_C * 4) return;
    const int k = t >> 2, h = t & 3;
    const int r = row[k], c = col[k];
    float a = ax[(size_t)r * 4 + h] + ae[(size_t)c * 4 + h];
    a = (a >= 0.f) ? a : 0.2f * a;
    alpha[t] = a;
    atomicMax(nmax + (size_t)r * 4 + h, fkey_enc(a));
}

__global__ __launch_bounds__(256) void alpha_exp_k(
    const int* __restrict__ row, const int* __restrict__ col,
    const float* __restrict__ adjv, float* __restrict__ alpha,
    const unsigned* __restrict__ nmax, float* __restrict__ nsum,
    float* __restrict__ Dn)
{
    const int t = blockIdx.x * 256 + threadIdx.x;
    if (t >= NNZ_C * 4) return;
    const int k = t >> 2, h = t & 3;
    const int r = row[k];
    const float m = fkey_dec(nmax[(size_t)r * 4 + h]);
    const float ex = __expf(alpha[t] - m);
    alpha[t] = ex;
    atomicAdd(nsum + (size_t)r * 4 + h, ex);
    if (h == 0) atomicAdd(Dn + r, adjv[col[k]]);
}

__global__ __launch_bounds__(256) void alpha_norm_k(
    const int* __restrict__ row, float* __restrict__ alpha,
    const float* __restrict__ nsum)
{
    const int t = blockIdx.x * 256 + threadIdx.x;
    if (t >= NNZ_C * 4) return;
    const int k = t >> 2, h = t & 3;
    alpha[t] /= nsum[(size_t)row[k] * 4 + h];
}

__global__ __launch_bounds__(256) void out_e_k(
    const int* __restrict__ row, const float* __restrict__ alpha,
    const unsigned short* __restrict__ Xlin, float* __restrict__ out_e)
{
    const int e = blockIdx.x * 2 + (threadIdx.x >> 7);
    const int f = threadIdx.x & 127;
    if (e >= ENUM) return;
    float a0 = 0.f, a1 = 0.f, a2 = 0.f, a3 = 0.f;
    #pragma unroll
    for (int j = 0; j < 8; j++) {
        const int k = e + j * ENUM;
        const int r = row[k];
        const unsigned short* xp = Xlin + (size_t)r * 512 + f;
        const float4 al = *(const float4*)(alpha + (size_t)k * 4);
        a0 += al.x * bf2f(xp[0]);
        a1 += al.y * bf2f(xp[128]);
        a2 += al.z * bf2f(xp[256]);
        a3 += al.w * bf2f(xp[384]);
    }
    float* op = out_e + (size_t)e * 512 + f;
    op[0]   = 0.125f * a0;
    op[128] = 0.125f * a1;
    op[256] = 0.125f * a2;
    op[384] = 0.125f * a3;
}

__global__ __launch_bounds__(256) void xres_init_k(
    float* __restrict__ Xres, const float* __restrict__ bias)
{
    const int t = blockIdx.x * 256 + threadIdx.x;
    if (t < NN * 128) Xres[t] = bias[t & 127];
}

__global__ __launch_bounds__(256) void scatter_k(
    const int* __restrict__ row, const int* __restrict__ col,
    const float* __restrict__ alpha, const float* __restrict__ Dn,
    const float* __restrict__ out_e, float* __restrict__ Xres)
{
    const int k = blockIdx.x * 2 + (threadIdx.x >> 7);
    const int f = threadIdx.x & 127;
    if (k >= NNZ_C) return;
    const int r = row[k], c = col[k];
    const float w = 0.25f / Dn[r];
    const float4 al = *(const float4*)(alpha + (size_t)k * 4);
    const float* ep = out_e + (size_t)c * 512 + f;
    const float v = w * (al.x * ep[0] + al.y * ep[128] +
                         al.z * ep[256] + al.w * ep[384]);
    atomicAdd(Xres + (size_t)r * 128 + f, v);
}

extern "C" void kernel_launch(void* const* d_in, const int* in_sizes, int n_in,
                              void* d_out, int out_size, void* d_ws, size_t ws_size,
                              hipStream_t stream)
{
    const float* X         = (const float*)d_in[0];
    const float* E         = (const float*)d_in[1];
    const int*   adj       = (const int*)d_in[2];
    const float* adjv      = (const float*)d_in[3];
    const float* Wn        = (const float*)d_in[4];
    const float* bn        = (const float*)d_in[5];
    const float* We        = (const float*)d_in[6];
    const float* be        = (const float*)d_in[7];
    const float* Wlin      = (const float*)d_in[8];
    const float* att       = (const float*)d_in[9];
    const float* bias_conv = (const float*)d_in[10];
    const int* row = adj;
    const int* col = adj + NNZ_C;

    float* Xres = (float*)d_out;
    float* Eres = Xres + (size_t)NN * 128;

    // workspace layout (~169 MB)
    char* wsb = (char*)d_ws;
    unsigned short* Xbf   = (unsigned short*)(wsb);              // [0, 25.6M)  dead after gemm4
    unsigned short* Xt    = (unsigned short*)(wsb + 25600000);   // [25.6M, 51.2M) dead after edge_agg
    unsigned short* EresB = (unsigned short*)(wsb + 25600000);   // aliases Xt (after edge_agg)
    unsigned short* elin  = (unsigned short*)(wsb);              // aliases Xbf (after gemm4)
    float*          out_e = (float*)(wsb);                       // [0, 51.2M) after elin/EresB dead
    unsigned short* Xlin  = (unsigned short*)(wsb + 51200000);   // 102.4 MB
    unsigned short* Ebf   = (unsigned short*)(wsb + 153600000);  // 6.4 MB
    unsigned short* WlinT = (unsigned short*)(wsb + 160000000);  // 128 KB
    unsigned short* WnT   = (unsigned short*)(wsb + 160131072);  // 32 KB
    unsigned short* WeT   = (unsigned short*)(wsb + 160163840);  // 32 KB
    float* ax    = (float*)(wsb + 160196608);                    // 1.6 MB
    float* ae    = (float*)(wsb + 161796608);                    // 0.4 MB
    float* alpha = (float*)(wsb + 162196608);                    // 3.2 MB
    unsigned* nmax = (unsigned*)(wsb + 165396608);               // 1.6 MB (nmax,nsum,Dn contiguous)
    float* nsum  = (float*)(wsb + 166996608);                    // 1.6 MB
    float* Dn    = (float*)(wsb + 168596608);                    // 0.4 MB

    zero_k<<<(NN * 9 + 255) / 256, 256, 0, stream>>>(nmax, NN * 9);

    // conversions / weight transposes
    convbf_k<<<(NN * 32 + 255) / 256, 256, 0, stream>>>(X, Xbf, NN * 32);
    convbf_k<<<(ENUM * 32 + 255) / 256, 256, 0, stream>>>(E, Ebf, ENUM * 32);
    wtr_k<<<256, 256, 0, stream>>>(Wlin, WlinT, 512);
    wtr_k<<<64, 256, 0, stream>>>(Wn, WnT, 128);
    wtr_k<<<64, 256, 0, stream>>>(We, WeT, 128);

    // 1. Xt = bf16(Xbf @ Wn + bn)
    gemm_mfma_k<true><<<dim3(1563, 2), 256, 0, stream>>>(Xbf, WnT, bn, nullptr, Xt, NN, 128);
    // 2. Eres = Ebf @ We + be + E   (f32 out)
    gemm_mfma_k<false><<<dim3(391, 2), 256, 0, stream>>>(Ebf, WeT, be, E, Eres, ENUM, 128);
    // 3. Eres += norm * agg (bf16 gather)
    edge_agg_k<<<ENUM / 2, 256, 0, stream>>>(row, adjv, Xt, Eres);
    // 4. Xlin = bf16(Xbf @ Wlin)
    gemm_mfma_k<true><<<dim3(1563, 8), 256, 0, stream>>>(Xbf, WlinT, nullptr, nullptr, Xlin, NN, 512);
    // 5. EresB = bf16(Eres); elin = bf16(EresB @ Wlin)
    convbf_k<<<(ENUM * 32 + 255) / 256, 256, 0, stream>>>(Eres, EresB, ENUM * 32);
    gemm_mfma_k<true><<<dim3(391, 8), 256, 0, stream>>>(EresB, WlinT, nullptr, nullptr, elin, ENUM, 512);
    // 6. attention dots
    att_dot_k<<<NN / 4, 256, 0, stream>>>(Xlin, att, ax, NN);
    att_dot_k<<<ENUM / 4, 256, 0, stream>>>(elin, att + 128, ae, ENUM);
    // 7-9. segment softmax over rows + Dn
    alpha_max_k<<<(NNZ_C * 4) / 256, 256, 0, stream>>>(row, col, ax, ae, alpha, nmax);
    alpha_exp_k<<<(NNZ_C * 4) / 256, 256, 0, stream>>>(row, col, adjv, alpha, nmax, nsum, Dn);
    alpha_norm_k<<<(NNZ_C * 4) / 256, 256, 0, stream>>>(row, alpha, nsum);
    // 10. node -> hyperedge aggregation
    out_e_k<<<ENUM / 2, 256, 0, stream>>>(row, alpha, Xlin, out_e);
    // 11-12. hyperedge -> node aggregation (+ bias, mean over heads)
    xres_init_k<<<(NN * 128) / 256, 256, 0, stream>>>(Xres, bias_conv);
    scatter_k<<<NNZ_C / 2, 256, 0, stream>>>(row, col, alpha, Dn, out_e, Xres);
}

// Round 4
// 345.981 us; speedup vs baseline: 1.5645x; 1.0478x over previous
//
#include <hip/hip_runtime.h>

#define NN 100000
#define ENUM 25000
#define NNZ_C 200000
// D = 128, H = 4, F = 128, Wlin: [128,512]

typedef __attribute__((ext_vector_type(8))) short bf16x8;
typedef __attribute__((ext_vector_type(4))) float f32x4;

__device__ __forceinline__ float bf2f(unsigned short v) {
    return __uint_as_float(((unsigned)v) << 16);
}
__device__ __forceinline__ unsigned short f2bf(float x) {
    unsigned u = __float_as_uint(x);
    unsigned r = (u + 0x7fff + ((u >> 16) & 1)) >> 16;   // round-to-nearest-even
    return (unsigned short)r;
}

// -------- f32 -> bf16 convert (4 elems/thread) --------
__global__ __launch_bounds__(256) void convbf_k(
    const float* __restrict__ in, unsigned short* __restrict__ out, int n4)
{
    const int t = blockIdx.x * 256 + threadIdx.x;
    if (t >= n4) return;
    const float4 a = ((const float4*)in)[t];
    ushort4 u;
    u.x = f2bf(a.x); u.y = f2bf(a.y); u.z = f2bf(a.z); u.w = f2bf(a.w);
    ((ushort4*)out)[t] = u;
}

// -------- W[128][NC] f32 -> Wt[NC][128] bf16 (transpose) --------
__global__ __launch_bounds__(256) void wtr_k(
    const float* __restrict__ W, unsigned short* __restrict__ Wt, int NC)
{
    const int t = blockIdx.x * 256 + threadIdx.x;
    if (t >= 128 * NC) return;
    const int c = t % NC, k = t / NC;
    Wt[c * 128 + k] = f2bf(W[t]);
}

// ---------------- MFMA GEMM: C[M,NC] = A[M,128] @ W[128,NC] (+bias)(+resid) ----
template <bool BF16OUT>
__global__ __launch_bounds__(256) void gemm_mfma_k(
    const unsigned short* __restrict__ A, const unsigned short* __restrict__ Wt,
    const float* __restrict__ bias, const float* __restrict__ resid,
    void* __restrict__ Cv, int M, int NC)
{
    __shared__ unsigned short As[64 * 128];
    __shared__ unsigned short Bs[64 * 128];
    const int tid = threadIdx.x;
    const int r0 = blockIdx.x * 64;
    const int c0 = blockIdx.y * 64;

    {
        int rr = tid >> 4;
        const int kc = (tid & 15) * 8;
        #pragma unroll
        for (int it = 0; it < 4; it++) {
            int r = r0 + rr; if (r > M - 1) r = M - 1;
            const uint4 va = *(const uint4*)(A + (size_t)r * 128 + kc);
            const uint4 vb = *(const uint4*)(Wt + (size_t)(c0 + rr) * 128 + kc);
            const int idx = (rr * 128 + kc) ^ ((rr & 7) << 3);
            *(uint4*)&As[idx] = va;
            *(uint4*)&Bs[idx] = vb;
            rr += 16;
        }
    }
    __syncthreads();

    const int lane = tid & 63;
    const int wid = tid >> 6;
    const int wr = wid >> 1, wc = wid & 1;
    const int fr = lane & 15;
    const int kg = (lane >> 4) * 8;

    f32x4 acc[2][2] = {};

    #pragma unroll
    for (int ks = 0; ks < 4; ks++) {
        bf16x8 a[2], b[2];
        #pragma unroll
        for (int m = 0; m < 2; m++) {
            const int ar = wr * 32 + m * 16 + fr;
            const int idx = (ar * 128 + ks * 32 + kg) ^ ((ar & 7) << 3);
            a[m] = *(const bf16x8*)&As[idx];
        }
        #pragma unroll
        for (int n = 0; n < 2; n++) {
            const int br = wc * 32 + n * 16 + fr;
            const int idx = (br * 128 + ks * 32 + kg) ^ ((br & 7) << 3);
            b[n] = *(const bf16x8*)&Bs[idx];
        }
        #pragma unroll
        for (int m = 0; m < 2; m++)
            #pragma unroll
            for (int n = 0; n < 2; n++)
                acc[m][n] = __builtin_amdgcn_mfma_f32_16x16x32_bf16(a[m], b[n], acc[m][n], 0, 0, 0);
    }

    #pragma unroll
    for (int m = 0; m < 2; m++) {
        #pragma unroll
        for (int n = 0; n < 2; n++) {
            const int c = c0 + wc * 32 + n * 16 + (lane & 15);
            #pragma unroll
            for (int j = 0; j < 4; j++) {
                const int r = r0 + wr * 32 + m * 16 + (lane >> 4) * 4 + j;
                if (r < M) {
                    float v = acc[m][n][j];
                    if (bias) v += bias[c];
                    if (resid) v += resid[(size_t)r * NC + c];
                    if (BF16OUT) ((unsigned short*)Cv)[(size_t)r * NC + c] = f2bf(v);
                    else         ((float*)Cv)[(size_t)r * NC + c] = v;
                }
            }
        }
    }
}

// -------- edge aggregation: Eres[e,:] += (1/deg_e) * sum_j adj[k] * Xt[row[k],:] ----
__global__ __launch_bounds__(256) void edge_agg_k(
    const int* __restrict__ row, const float* __restrict__ adjv,
    const unsigned short* __restrict__ Xt, float* __restrict__ Eres)
{
    const int e = blockIdx.x * 2 + (threadIdx.x >> 7);
    const int f = threadIdx.x & 127;
    if (e >= ENUM) return;
    float acc = 0.f, deg = 0.f;
    #pragma unroll
    for (int j = 0; j < 8; j++) {
        const int k = e + j * ENUM;
        const float v = adjv[k];
        deg += v;
        acc += v * bf2f(Xt[(size_t)row[k] * 128 + f]);
    }
    Eres[(size_t)e * 128 + f] += acc / deg;
}

// -------- per-row attention dot (bf16 feat) --------
__global__ __launch_bounds__(256) void att_dot_k(
    const unsigned short* __restrict__ feat, const float* __restrict__ att,
    float* __restrict__ out, int M)
{
    const int wid = (blockIdx.x * 256 + threadIdx.x) >> 6;
    const int lane = threadIdx.x & 63;
    if (wid >= M) return;
    const int h = lane >> 4;
    const int f0 = (lane & 15) * 8;
    const unsigned short* fp = feat + (size_t)wid * 512 + h * 128 + f0;
    const float* ap = att + h * 256 + f0;
    const uint4 u = *(const uint4*)fp;
    float s = 0.f;
    s += __uint_as_float(u.x << 16)         * ap[0];
    s += __uint_as_float(u.x & 0xFFFF0000u) * ap[1];
    s += __uint_as_float(u.y << 16)         * ap[2];
    s += __uint_as_float(u.y & 0xFFFF0000u) * ap[3];
    s += __uint_as_float(u.z << 16)         * ap[4];
    s += __uint_as_float(u.z & 0xFFFF0000u) * ap[5];
    s += __uint_as_float(u.w << 16)         * ap[6];
    s += __uint_as_float(u.w & 0xFFFF0000u) * ap[7];
    s += __shfl_xor(s, 1); s += __shfl_xor(s, 2);
    s += __shfl_xor(s, 4); s += __shfl_xor(s, 8);
    if ((lane & 15) == 0) out[(size_t)wid * 4 + h] = s;
}

// -------- CSR build --------
__global__ __launch_bounds__(256) void zero_k(unsigned* __restrict__ p, int n)
{
    const int t = blockIdx.x * 256 + threadIdx.x;
    if (t < n) p[t] = 0u;
}

__global__ __launch_bounds__(256) void hist_k(
    const int* __restrict__ row, int* __restrict__ cnt)
{
    const int k = blockIdx.x * 256 + threadIdx.x;
    if (k < NNZ_C) atomicAdd(cnt + row[k], 1);
}

// per-block exclusive scan; block totals to bsum
__global__ __launch_bounds__(256) void scan1_k(
    const int* __restrict__ cnt, int* __restrict__ rp, int* __restrict__ bsum, int n)
{
    __shared__ int sh[256];
    const int t = threadIdx.x, g = blockIdx.x * 256 + t;
    const int v = (g < n) ? cnt[g] : 0;
    sh[t] = v; __syncthreads();
    #pragma unroll
    for (int off = 1; off < 256; off <<= 1) {
        const int add = (t >= off) ? sh[t - off] : 0;
        __syncthreads();
        sh[t] += add;
        __syncthreads();
    }
    if (g < n) rp[g] = sh[t] - v;          // exclusive
    if (t == 255) bsum[blockIdx.x] = sh[255];
}

// single-block exclusive scan of bsum (nb <= 512)
__global__ __launch_bounds__(512) void scan2_k(int* __restrict__ bsum, int nb)
{
    __shared__ int sh[512];
    const int t = threadIdx.x;
    const int v = (t < nb) ? bsum[t] : 0;
    sh[t] = v; __syncthreads();
    #pragma unroll
    for (int off = 1; off < 512; off <<= 1) {
        const int add = (t >= off) ? sh[t - off] : 0;
        __syncthreads();
        sh[t] += add;
        __syncthreads();
    }
    if (t < nb) bsum[t] = sh[t] - v;       // exclusive
}

// add block offsets; copy to cursor; set rp[n]=NNZ
__global__ __launch_bounds__(256) void scan3_k(
    int* __restrict__ rp, const int* __restrict__ bsum, int* __restrict__ cur, int n)
{
    const int g = blockIdx.x * 256 + threadIdx.x;
    if (g < n) {
        const int v = rp[g] + bsum[g >> 8];
        rp[g] = v;
        cur[g] = v;
    }
    if (g == 0) rp[n] = NNZ_C;
}

__global__ __launch_bounds__(256) void fill_k(
    const int* __restrict__ row, int* __restrict__ cur, int* __restrict__ eidx)
{
    const int k = blockIdx.x * 256 + threadIdx.x;
    if (k < NNZ_C) {
        const int p = atomicAdd(cur + row[k], 1);
        eidx[p] = k;
    }
}

// -------- CSR segment softmax: alpha[k,h] normalized over edges of row[k] ----
__global__ __launch_bounds__(256) void softmax_csr_k(
    const int* __restrict__ rowptr, const int* __restrict__ eidx,
    const int* __restrict__ col, const float* __restrict__ ax,
    const float* __restrict__ ae, float* __restrict__ alpha)
{
    const int t = blockIdx.x * 256 + threadIdx.x;
    if (t >= NN * 4) return;
    const int r = t >> 2, h = t & 3;
    const int p0 = rowptr[r], p1 = rowptr[r + 1];
    if (p0 == p1) return;
    const float axv = ax[t];
    float m = -1e30f;
    for (int p = p0; p < p1; ++p) {
        const int c = col[eidx[p]];
        float a = axv + ae[c * 4 + h];
        a = (a >= 0.f) ? a : 0.2f * a;
        m = fmaxf(m, a);
    }
    float s = 0.f;
    for (int p = p0; p < p1; ++p) {
        const int k = eidx[p];
        const int c = col[k];
        float a = axv + ae[c * 4 + h];
        a = (a >= 0.f) ? a : 0.2f * a;
        const float e = __expf(a - m);
        s += e;
        alpha[(size_t)k * 4 + h] = e;
    }
    const float rs = 1.f / s;
    for (int p = p0; p < p1; ++p)
        alpha[(size_t)eidx[p] * 4 + h] *= rs;
}

// -------- out_e[e,h,f] = (1/8) sum_j alpha[k,h] * Xlin[row[k], h*128+f]  (bf16 out) ----
__global__ __launch_bounds__(256) void out_e_k(
    const int* __restrict__ row, const float* __restrict__ alpha,
    const unsigned short* __restrict__ Xlin, unsigned short* __restrict__ out_e)
{
    const int e = blockIdx.x * 2 + (threadIdx.x >> 7);
    const int f = threadIdx.x & 127;
    if (e >= ENUM) return;
    float a0 = 0.f, a1 = 0.f, a2 = 0.f, a3 = 0.f;
    #pragma unroll
    for (int j = 0; j < 8; j++) {
        const int k = e + j * ENUM;
        const int r = row[k];
        const unsigned short* xp = Xlin + (size_t)r * 512 + f;
        const float4 al = *(const float4*)(alpha + (size_t)k * 4);
        a0 += al.x * bf2f(xp[0]);
        a1 += al.y * bf2f(xp[128]);
        a2 += al.z * bf2f(xp[256]);
        a3 += al.w * bf2f(xp[384]);
    }
    unsigned short* op = out_e + (size_t)e * 512 + f;
    op[0]   = f2bf(0.125f * a0);
    op[128] = f2bf(0.125f * a1);
    op[256] = f2bf(0.125f * a2);
    op[384] = f2bf(0.125f * a3);
}

// -------- final CSR gather: Xres[r,f] = bias[f] + (0.25/Dn_r) sum_k sum_h alpha*out_e ----
__global__ __launch_bounds__(256) void xgather_k(
    const int* __restrict__ rowptr, const int* __restrict__ eidx,
    const int* __restrict__ col, const float* __restrict__ adjv,
    const float* __restrict__ alpha, const unsigned short* __restrict__ out_e,
    const float* __restrict__ bias, float* __restrict__ Xres)
{
    const int r = blockIdx.x * 2 + (threadIdx.x >> 7);
    const int f = threadIdx.x & 127;
    if (r >= NN) return;
    const int p0 = rowptr[r], p1 = rowptr[r + 1];
    float acc = 0.f, dsum = 0.f;
    for (int p = p0; p < p1; ++p) {
        const int k = eidx[p];
        const int c = col[k];
        dsum += adjv[c];
        const float4 al = *(const float4*)(alpha + (size_t)k * 4);
        const unsigned short* ep = out_e + (size_t)c * 512 + f;
        acc += al.x * bf2f(ep[0])   + al.y * bf2f(ep[128])
             + al.z * bf2f(ep[256]) + al.w * bf2f(ep[384]);
    }
    const float w = (p1 > p0) ? 0.25f / dsum : 0.f;
    Xres[(size_t)r * 128 + f] = bias[f] + w * acc;
}

extern "C" void kernel_launch(void* const* d_in, const int* in_sizes, int n_in,
                              void* d_out, int out_size, void* d_ws, size_t ws_size,
                              hipStream_t stream)
{
    const float* X         = (const float*)d_in[0];
    const float* E         = (const float*)d_in[1];
    const int*   adj       = (const int*)d_in[2];
    const float* adjv      = (const float*)d_in[3];
    const float* Wn        = (const float*)d_in[4];
    const float* bn        = (const float*)d_in[5];
    const float* We        = (const float*)d_in[6];
    const float* be        = (const float*)d_in[7];
    const float* Wlin      = (const float*)d_in[8];
    const float* att       = (const float*)d_in[9];
    const float* bias_conv = (const float*)d_in[10];
    const int* row = adj;
    const int* col = adj + NNZ_C;

    float* Xres = (float*)d_out;
    float* Eres = Xres + (size_t)NN * 128;

    // workspace layout (~167 MB)
    char* wsb = (char*)d_ws;
    unsigned short* Xbf   = (unsigned short*)(wsb);              // [0, 25.6M)
    unsigned short* Xt    = (unsigned short*)(wsb + 25600000);   // [25.6M, 51.2M)
    unsigned short* EresB = (unsigned short*)(wsb + 25600000);   // aliases Xt
    unsigned short* elin  = (unsigned short*)(wsb);              // aliases Xbf
    unsigned short* out_e = (unsigned short*)(wsb);              // aliases elin (dead after att_dot)
    unsigned short* Xlin  = (unsigned short*)(wsb + 51200000);   // 102.4 MB
    unsigned short* Ebf   = (unsigned short*)(wsb + 153600000);  // 6.4 MB
    unsigned short* WlinT = (unsigned short*)(wsb + 160000000);  // 128 KB
    unsigned short* WnT   = (unsigned short*)(wsb + 160131072);  // 32 KB
    unsigned short* WeT   = (unsigned short*)(wsb + 160163840);  // 32 KB
    float* ax    = (float*)(wsb + 160196608);                    // 1.6 MB
    float* ae    = (float*)(wsb + 161796608);                    // 0.4 MB
    float* alpha = (float*)(wsb + 162196608);                    // 3.2 MB
    int* rowptr  = (int*)(wsb + 165396608);                      // 400,016 B
    int* cnt     = (int*)(wsb + 165796624);                      // 400,000 B (reused as cursor)
    int* eidx    = (int*)(wsb + 166196624);                      // 800,000 B
    int* bsum    = (int*)(wsb + 166996624);                      // 2 KB

    // ---- CSR build (independent of GEMMs) ----
    zero_k<<<(NN + 255) / 256, 256, 0, stream>>>((unsigned*)cnt, NN);
    hist_k<<<(NNZ_C + 255) / 256, 256, 0, stream>>>(row, cnt);
    scan1_k<<<(NN + 255) / 256, 256, 0, stream>>>(cnt, rowptr, bsum, NN);
    scan2_k<<<1, 512, 0, stream>>>(bsum, (NN + 255) / 256);
    scan3_k<<<(NN + 255) / 256, 256, 0, stream>>>(rowptr, bsum, cnt, NN);
    fill_k<<<(NNZ_C + 255) / 256, 256, 0, stream>>>(row, cnt, eidx);

    // ---- conversions / weight transposes ----
    convbf_k<<<(NN * 32 + 255) / 256, 256, 0, stream>>>(X, Xbf, NN * 32);
    convbf_k<<<(ENUM * 32 + 255) / 256, 256, 0, stream>>>(E, Ebf, ENUM * 32);
    wtr_k<<<256, 256, 0, stream>>>(Wlin, WlinT, 512);
    wtr_k<<<64, 256, 0, stream>>>(Wn, WnT, 128);
    wtr_k<<<64, 256, 0, stream>>>(We, WeT, 128);

    // ---- dense pipeline ----
    gemm_mfma_k<true><<<dim3(1563, 2), 256, 0, stream>>>(Xbf, WnT, bn, nullptr, Xt, NN, 128);
    gemm_mfma_k<false><<<dim3(391, 2), 256, 0, stream>>>(Ebf, WeT, be, E, Eres, ENUM, 128);
    edge_agg_k<<<ENUM / 2, 256, 0, stream>>>(row, adjv, Xt, Eres);
    gemm_mfma_k<true><<<dim3(1563, 8), 256, 0, stream>>>(Xbf, WlinT, nullptr, nullptr, Xlin, NN, 512);
    convbf_k<<<(ENUM * 32 + 255) / 256, 256, 0, stream>>>(Eres, EresB, ENUM * 32);
    gemm_mfma_k<true><<<dim3(391, 8), 256, 0, stream>>>(EresB, WlinT, nullptr, nullptr, elin, ENUM, 512);

    // ---- attention dots ----
    att_dot_k<<<NN / 4, 256, 0, stream>>>(Xlin, att, ax, NN);
    att_dot_k<<<ENUM / 4, 256, 0, stream>>>(elin, att + 128, ae, ENUM);

    // ---- CSR softmax ----
    softmax_csr_k<<<(NN * 4) / 256 + 1, 256, 0, stream>>>(rowptr, eidx, col, ax, ae, alpha);

    // ---- node -> hyperedge (out_e overwrites elin; elin consumed above) ----
    out_e_k<<<ENUM / 2, 256, 0, stream>>>(row, alpha, Xlin, out_e);

    // ---- hyperedge -> node: atomic-free CSR gather ----
    xgather_k<<<NN / 2, 256, 0, stream>>>(rowptr, eidx, col, adjv, alpha, out_e, bias_conv, Xres);
}